// Round 3
// baseline (328.749 us; speedup 1.0000x reference)
//
#include <hip/hip_runtime.h>
#include <hip/hip_bf16.h>

typedef unsigned short u16;
typedef unsigned int   u32;
typedef _Float16 f16;
typedef _Float16 f16x8 __attribute__((ext_vector_type(8)));
typedef float    f32x4 __attribute__((ext_vector_type(4)));
typedef float    f32x8 __attribute__((ext_vector_type(8)));

#define BATCH 8
#define SEQ   4096
#define EMB   512
#define NCOL  512   // H*d = 8*64

// ---------------------------------------------------------------------------
__device__ __forceinline__ void gll16(const void* g, void* l) {
  __builtin_amdgcn_global_load_lds((__attribute__((address_space(1))) void*)g,
                                   (__attribute__((address_space(3))) void*)l,
                                   16, 0, 0);
}

// ---------------------------------------------------------------------------
// Prepass: 5 planes, transpose W (f32 [k=512][n=512]) into f16 [n][k]:
//   z=0 WQ-hi, 1 WQ-lo(x256), 2 WK-hi, 3 WK-lo(x256), 4 WV.
// hi = rn_f16(x); lo = rn_f16((x-hi)*256)  ->  x = hi + lo/256 to ~2^-23 rel.
__global__ __launch_bounds__(256) void prep_w(
    const float* __restrict__ Wq, const float* __restrict__ Wk,
    const float* __restrict__ Wv, u16* __restrict__ out)
{
  __shared__ u16 tile[64][65];
  const int z = blockIdx.z;
  const float* in = (z < 2) ? Wq : (z < 4) ? Wk : Wv;
  const bool lo = (z == 1 || z == 3);
  u16* o = out + (size_t)z * EMB * NCOL;
  const int r0 = blockIdx.y * 64, c0 = blockIdx.x * 64;
  const int tx = threadIdx.x, ty = threadIdx.y;
#pragma unroll
  for (int i = 0; i < 16; ++i) {
    const int r = ty * 16 + i;
    const float x = in[(size_t)(r0 + r) * NCOL + (c0 + tx)];
    const f16 h = (f16)x;
    const f16 v = lo ? (f16)((x - (float)h) * 256.0f) : h;
    tile[r][tx] = __builtin_bit_cast(u16, v);
  }
  __syncthreads();
#pragma unroll
  for (int i = 0; i < 16; ++i) {
    const int rr = ty * 16 + i;
    o[(size_t)(c0 + rr) * EMB + (r0 + tx)] = tile[tx][rr];
  }
}

// ---------------------------------------------------------------------------
// Fused: Q/K/V projections (Q,K split-f16: hh -> acc, xh*wl + xl*wh -> accc,
// recombine q = acc + accc/256) for a 64-row x 128-col tile, then a = q*k/8,
// V_len mask, softmax over each 64-col head group, out = sm * v * (s<Q_len).
// 4 waves: wave w -> rows (w>>1)*32..+31, cols (w&1)*64..+63 (one head group).
__global__ __launch_bounds__(256, 2) void fused_attn(
    const float* __restrict__ Xq, const float* __restrict__ Xk,
    const float* __restrict__ Xv,
    const int* __restrict__ Qlen, const int* __restrict__ Vlen,
    const u16* __restrict__ Wt,   // 5 planes of [512 n][512 k] f16
    float* __restrict__ out)
{
  const int b  = blockIdx.z;
  const int s0 = blockIdx.x * 64;
  const int c0 = blockIdx.y * 128;
  const int qlen = Qlen[b];
  const int t = threadIdx.x;

  if (s0 >= qlen) {           // fully masked tile: write zeros
    const f32x4 z4 = {0.f, 0.f, 0.f, 0.f};
#pragma unroll
    for (int it = 0; it < 8; ++it) {
      const int f4  = it * 256 + t;
      const int row = f4 >> 5;
      const int col = (f4 & 31) * 4;
      *(f32x4*)(out + (size_t)(b * SEQ + s0 + row) * NCOL + c0 + col) = z4;
    }
    return;
  }
  const int vlen = Vlen[b];
  const int vl = (vlen == 0) ? 64 : vlen;  // all-masked: -1e12 shift cancels

  __shared__ unsigned char smem[65536] __attribute__((aligned(16)));
  float* Xq_s  = (float*)(smem);            // [64][32] f32
  float* Xk_s  = (float*)(smem + 8192);
  float* Xv_s  = (float*)(smem + 16384);
  u16*   Wqh_s = (u16*)(smem + 24576);      // [128][32] f16
  u16*   Wql_s = (u16*)(smem + 32768);
  u16*   Wkh_s = (u16*)(smem + 40960);
  u16*   Wkl_s = (u16*)(smem + 49152);
  u16*   Wv_s  = (u16*)(smem + 57344);

  const u16* Wqh_g = Wt;
  const u16* Wql_g = Wt + 1 * EMB * NCOL;
  const u16* Wkh_g = Wt + 2 * EMB * NCOL;
  const u16* Wkl_g = Wt + 3 * EMB * NCOL;
  const u16* Wv_g  = Wt + 4 * EMB * NCOL;

  f32x4 accQ[2][4], accQc[2][4], accK[2][4], accKc[2][4], accV[2][4];
#pragma unroll
  for (int rt = 0; rt < 2; ++rt)
#pragma unroll
    for (int ct = 0; ct < 4; ++ct) {
      const f32x4 z = {0.f, 0.f, 0.f, 0.f};
      accQ[rt][ct] = z; accQc[rt][ct] = z;
      accK[rt][ct] = z; accKc[rt][ct] = z;
      accV[rt][ct] = z;
    }

  const int w    = t >> 6;
  const int lane = t & 63;
  const int quad = lane >> 4;
  const int l15  = lane & 15;
  const int wr   = w >> 1;
  const int wc   = w & 1;

  // staging: X f32 (16B = 4 floats/lane), W f16 (16B = 8 elems/lane)
  const int xrow = t >> 3;                 // 0..31
  const int k4   = (t & 7) * 4;
  const size_t xg = (size_t)(b * SEQ + s0 + xrow) * EMB + k4;
  const int wn   = t >> 2;                 // 0..63
  const int k8   = (t & 3) * 8;
  const int wg   = (c0 + wn) * EMB + k8;
  const int xl   = t * 4;                  // f32 elements
  const int wlo  = t * 8;                  // u16 elements

  for (int kk = 0; kk < EMB; kk += 32) {
    __syncthreads();
    gll16(Xq + xg + kk,             Xq_s + xl);
    gll16(Xq + xg + 32 * EMB + kk,  Xq_s + 1024 + xl);
    gll16(Xk + xg + kk,             Xk_s + xl);
    gll16(Xk + xg + 32 * EMB + kk,  Xk_s + 1024 + xl);
    gll16(Xv + xg + kk,             Xv_s + xl);
    gll16(Xv + xg + 32 * EMB + kk,  Xv_s + 1024 + xl);
    gll16(Wqh_g + wg + kk,            Wqh_s + wlo);
    gll16(Wqh_g + wg + 64 * EMB + kk, Wqh_s + 2048 + wlo);
    gll16(Wql_g + wg + kk,            Wql_s + wlo);
    gll16(Wql_g + wg + 64 * EMB + kk, Wql_s + 2048 + wlo);
    gll16(Wkh_g + wg + kk,            Wkh_s + wlo);
    gll16(Wkh_g + wg + 64 * EMB + kk, Wkh_s + 2048 + wlo);
    gll16(Wkl_g + wg + kk,            Wkl_s + wlo);
    gll16(Wkl_g + wg + 64 * EMB + kk, Wkl_s + 2048 + wlo);
    gll16(Wv_g + wg + kk,             Wv_s + wlo);
    gll16(Wv_g + wg + 64 * EMB + kk,  Wv_s + 2048 + wlo);
    __syncthreads();

    // A fragments: f32 -> f16 hi + f16 lo*256 split in registers
    f16x8 aqh[2], aql[2], akh[2], akl[2], av[2];
#pragma unroll
    for (int rt = 0; rt < 2; ++rt) {
      const int ao = (wr * 32 + rt * 16 + l15) * 32 + quad * 8;
      const f32x8 xq = *(const f32x8*)(Xq_s + ao);
      const f32x8 xk = *(const f32x8*)(Xk_s + ao);
      const f32x8 xv = *(const f32x8*)(Xv_s + ao);
#pragma unroll
      for (int j = 0; j < 8; ++j) {
        const float q = xq[j];
        const f16 qh = (f16)q;
        aqh[rt][j] = qh;
        aql[rt][j] = (f16)((q - (float)qh) * 256.0f);
        const float k = xk[j];
        const f16 kh = (f16)k;
        akh[rt][j] = kh;
        akl[rt][j] = (f16)((k - (float)kh) * 256.0f);
        av[rt][j]  = (f16)xv[j];
      }
    }
#pragma unroll
    for (int ct = 0; ct < 4; ++ct) {
      const int bo = (wc * 64 + ct * 16 + l15) * 32 + quad * 8;
      const f16x8 bqh = *(const f16x8*)(Wqh_s + bo);
      const f16x8 bql = *(const f16x8*)(Wql_s + bo);
      const f16x8 bkh = *(const f16x8*)(Wkh_s + bo);
      const f16x8 bkl = *(const f16x8*)(Wkl_s + bo);
      const f16x8 bv  = *(const f16x8*)(Wv_s  + bo);
#pragma unroll
      for (int rt = 0; rt < 2; ++rt) {
        accQ [rt][ct] = __builtin_amdgcn_mfma_f32_16x16x32_f16(aqh[rt], bqh, accQ [rt][ct], 0, 0, 0);
        accQc[rt][ct] = __builtin_amdgcn_mfma_f32_16x16x32_f16(aqh[rt], bql, accQc[rt][ct], 0, 0, 0);
        accQc[rt][ct] = __builtin_amdgcn_mfma_f32_16x16x32_f16(aql[rt], bqh, accQc[rt][ct], 0, 0, 0);
        accK [rt][ct] = __builtin_amdgcn_mfma_f32_16x16x32_f16(akh[rt], bkh, accK [rt][ct], 0, 0, 0);
        accKc[rt][ct] = __builtin_amdgcn_mfma_f32_16x16x32_f16(akh[rt], bkl, accKc[rt][ct], 0, 0, 0);
        accKc[rt][ct] = __builtin_amdgcn_mfma_f32_16x16x32_f16(akl[rt], bkh, accKc[rt][ct], 0, 0, 0);
        accV [rt][ct] = __builtin_amdgcn_mfma_f32_16x16x32_f16(av[rt],  bv,  accV [rt][ct], 0, 0, 0);
      }
    }
  }

  // Epilogue: C/D layout row = quad*4 + r, col = l15 (m89-verified).
  const float scale = 0.125f;     // 1/sqrt(64)
  const float rs    = 1.0f / 256.0f;
#pragma unroll
  for (int rt = 0; rt < 2; ++rt) {
#pragma unroll
    for (int r = 0; r < 4; ++r) {
      const int s = s0 + wr * 32 + rt * 16 + quad * 4 + r;
      const float qm = (s < qlen) ? 1.0f : 0.0f;
      float a[4]; bool msk[4];
      float mx = -3.0e38f;
#pragma unroll
      for (int ct = 0; ct < 4; ++ct) {
        const float q = accQ[rt][ct][r] + accQc[rt][ct][r] * rs;
        const float k = accK[rt][ct][r] + accKc[rt][ct][r] * rs;
        const float v = q * k * scale;
        a[ct] = v;
        msk[ct] = (ct * 16 + l15) < vl;
        if (msk[ct]) mx = fmaxf(mx, v);
      }
#pragma unroll
      for (int off = 1; off < 16; off <<= 1) mx = fmaxf(mx, __shfl_xor(mx, off));
      float e[4], sum = 0.f;
#pragma unroll
      for (int ct = 0; ct < 4; ++ct) {
        e[ct] = msk[ct] ? __expf(a[ct] - mx) : 0.0f;
        sum += e[ct];
      }
#pragma unroll
      for (int off = 1; off < 16; off <<= 1) sum += __shfl_xor(sum, off);
      const float inv = qm / sum;
      const size_t ob = (size_t)(b * SEQ + s) * NCOL + c0 + wc * 64 + l15;
#pragma unroll
      for (int ct = 0; ct < 4; ++ct) {
        out[ob + ct * 16] = e[ct] * inv * accV[rt][ct][r];
      }
    }
  }
}

// ---------------------------------------------------------------------------
extern "C" void kernel_launch(void* const* d_in, const int* in_sizes, int n_in,
                              void* d_out, int out_size, void* d_ws, size_t ws_size,
                              hipStream_t stream) {
  const float* Xq   = (const float*)d_in[0];
  const float* Xk   = (const float*)d_in[1];
  const float* Xv   = (const float*)d_in[2];
  const int*   Qlen = (const int*)d_in[3];
  const int*   Vlen = (const int*)d_in[4];
  const float* Wq   = (const float*)d_in[5];
  const float* Wk   = (const float*)d_in[6];
  const float* Wv   = (const float*)d_in[7];
  u16*   Wt  = (u16*)d_ws;              // 5 * 512*512 * 2B = 2.5 MB
  float* out = (float*)d_out;

  dim3 pg(8, 8, 5), pb(64, 4, 1);
  prep_w<<<pg, pb, 0, stream>>>(Wq, Wk, Wv, Wt);

  dim3 g(SEQ / 64, NCOL / 128, BATCH), blk(256, 1, 1);
  fused_attn<<<g, blk, 0, stream>>>(Xq, Xk, Xv, Qlen, Vlen, Wt, out);
}